// Round 7
// baseline (884.139 us; speedup 1.0000x reference)
//
#include <hip/hip_runtime.h>
#include <math.h>

#define NND 50000
#define EPSB 1e-5f
#define SLOPE 0.2f
#define NB 256      // dst buckets for counting-sort CSR build
#define SBLK 128    // scatter blocks (chunks of the edge list)
#define BRANGE 196  // nodes per bucket: ceil(50000/256)

__device__ __forceinline__ float lrelu(float v) { return v > 0.f ? v : SLOPE * v; }

__device__ __forceinline__ ushort f2bf(float f) {
    unsigned u = __float_as_uint(f);
    unsigned r = (u + 0x7fffu + ((u >> 16) & 1u)) >> 16;  // RNE
    return (ushort)r;
}

__device__ __forceinline__ void acc8(float* a, uint4 w, float e) {
    a[0] += e * __uint_as_float(w.x << 16);
    a[1] += e * __uint_as_float(w.x & 0xffff0000u);
    a[2] += e * __uint_as_float(w.y << 16);
    a[3] += e * __uint_as_float(w.y & 0xffff0000u);
    a[4] += e * __uint_as_float(w.z << 16);
    a[5] += e * __uint_as_float(w.z & 0xffff0000u);
    a[6] += e * __uint_as_float(w.w << 16);
    a[7] += e * __uint_as_float(w.w & 0xffff0000u);
}

// ---------------- graph build: counting-sort CSR (write-locality-friendly) ----------------

__global__ __launch_bounds__(256) void countC_kernel(const int* __restrict__ ei, int E,
                                                     int* __restrict__ cnt, int* __restrict__ C) {
    __shared__ int lc[NB];
    const int tid = threadIdx.x;
    for (int i = tid; i < NB; i += 256) lc[i] = 0;
    __syncthreads();
    const int per = (E + SBLK - 1) / SBLK;
    const int beg = blockIdx.x * per;
    const int end = min(beg + per, E);
    for (int i = beg + tid; i < end; i += 256) {
        int d = __builtin_nontemporal_load(&ei[E + i]);
        atomicAdd(&cnt[d], 1);
        atomicAdd(&lc[d / BRANGE], 1);
    }
    __syncthreads();
    for (int i = tid; i < NB; i += 256) C[i * SBLK + blockIdx.x] = lc[i];
}

__global__ __launch_bounds__(1024) void scanC_kernel(int* __restrict__ C) {
    __shared__ int ps[1024];
    const int t = threadIdx.x;
    int v[NB * SBLK / 1024];
    int s = 0;
#pragma unroll
    for (int j = 0; j < NB * SBLK / 1024; j++) {
        v[j] = C[t * (NB * SBLK / 1024) + j];
        s += v[j];
    }
    ps[t] = s;
    __syncthreads();
    for (int off = 1; off < 1024; off <<= 1) {
        int x = (t >= off) ? ps[t - off] : 0;
        __syncthreads();
        ps[t] += x;
        __syncthreads();
    }
    int ex = ps[t] - s;
#pragma unroll
    for (int j = 0; j < NB * SBLK / 1024; j++) {
        int tmp = v[j];
        C[t * (NB * SBLK / 1024) + j] = ex;
        ex += tmp;
    }
}

__global__ __launch_bounds__(256) void scatter_pairs_kernel(const int* __restrict__ ei, int E,
                                                            const int* __restrict__ C,
                                                            unsigned long long* __restrict__ pairs) {
    __shared__ int woff[NB];
    const int tid = threadIdx.x;
    for (int i = tid; i < NB; i += 256) woff[i] = C[i * SBLK + blockIdx.x];
    __syncthreads();
    const int per = (E + SBLK - 1) / SBLK;
    const int beg = blockIdx.x * per;
    const int end = min(beg + per, E);
    for (int i = beg + tid; i < end; i += 256) {
        int s = __builtin_nontemporal_load(&ei[i]);
        int d = __builtin_nontemporal_load(&ei[E + i]);
        int p = atomicAdd(&woff[d / BRANGE], 1);
        pairs[p] = ((unsigned long long)(unsigned)d << 32) | (unsigned)s;
    }
}

__global__ void scan1_kernel(const int* __restrict__ in, int n, int* __restrict__ outex,
                             int* __restrict__ bsum) {
    __shared__ int tmp[256];
    int tid = threadIdx.x;
    int i = blockIdx.x * 256 + tid;
    int v = (i < n) ? in[i] + 1 : 0;  // +1 self loop
    tmp[tid] = v;
    __syncthreads();
    for (int off = 1; off < 256; off <<= 1) {
        int t = (tid >= off) ? tmp[tid - off] : 0;
        __syncthreads();
        tmp[tid] += t;
        __syncthreads();
    }
    if (i < n) outex[i] = tmp[tid] - v;
    if (tid == 255) bsum[blockIdx.x] = tmp[255];
}

__global__ void scan2_kernel(const int* __restrict__ in, int n, int* __restrict__ outex) {
    __shared__ int tmp[256];
    int tid = threadIdx.x;
    int v = (tid < n) ? in[tid] : 0;
    tmp[tid] = v;
    __syncthreads();
    for (int off = 1; off < 256; off <<= 1) {
        int t = (tid >= off) ? tmp[tid - off] : 0;
        __syncthreads();
        tmp[tid] += t;
        __syncthreads();
    }
    if (tid < n) outex[tid] = tmp[tid] - v;
}

__global__ void scan3_kernel(int* __restrict__ rp, const int* __restrict__ boff,
                             int* __restrict__ fill, int* __restrict__ srcs, int n, int etot) {
    int i = blockIdx.x * 256 + threadIdx.x;
    if (i < n) {
        int v = rp[i] + boff[blockIdx.x];
        rp[i] = v;
        srcs[v] = i;  // self loop at row head
        fill[i] = v + 1;
    }
    if (i == 0) rp[n] = etot;
}

__global__ __launch_bounds__(256) void bucket_csr_kernel(const unsigned long long* __restrict__ pairs,
                                                         int E, const int* __restrict__ C,
                                                         int* __restrict__ fill,
                                                         int* __restrict__ srcs) {
    const int b = blockIdx.x;
    const int beg = C[b * SBLK];
    const int end = (b == NB - 1) ? E : C[(b + 1) * SBLK];
    for (int i = beg + threadIdx.x; i < end; i += 256) {
        unsigned long long pr = __builtin_nontemporal_load(&pairs[i]);
        int d = (int)(pr >> 32);
        int s = (int)(pr & 0xffffffffu);
        int p = atomicAdd(&fill[d], 1);
        srcs[p] = s;
    }
}

// ---------------- dense: h = X' @ W^T, fused input-BN, bf16 h output, fused alpha ---------

template <int K, int FOUT>
__global__ __launch_bounds__(256) void gemm_kernel(
    const float* __restrict__ X, const float* __restrict__ W, ushort* __restrict__ H, int n,
    const float* __restrict__ bnsum, const float* __restrict__ bnsq, const float* __restrict__ g,
    const float* __restrict__ be, const float* __restrict__ asrc, const float* __restrict__ adst,
    float* __restrict__ as_o, float* __restrict__ ad_o) {
    constexpr int SW = FOUT + 4;
    constexpr int SX = 68;
    constexpr int NF = FOUT / 64;
    __shared__ float Wt[64 * SW];
    __shared__ float Xt[64 * SX];
    __shared__ float bnsc[K];
    __shared__ float bnsh[K];
    const int tid = threadIdx.x;
    const int nodeBase = blockIdx.x * 64;
    const int tx = tid & 15, ty = tid >> 4;
    const bool doBN = (bnsum != nullptr);

    if (doBN) {
        const float invn = 1.f / (float)NND;
        for (int f = tid; f < K; f += 256) {
            float mu = bnsum[f] * invn;
            float var = bnsq[f] * invn - mu * mu;
            float r = rsqrtf(var + EPSB);
            float sc = g[f] * r;
            bnsc[f] = sc;
            bnsh[f] = be[f] - mu * sc;
        }
    }
    __syncthreads();

    float acc[4][4 * NF];
#pragma unroll
    for (int i = 0; i < 4; i++)
#pragma unroll
        for (int j = 0; j < 4 * NF; j++) acc[i][j] = 0.f;

    for (int kc = 0; kc < K; kc += 64) {
        for (int idx = tid; idx < FOUT * 64; idx += 256) {
            int f = idx >> 6, kk = idx & 63;
            Wt[kk * SW + f] = W[f * K + kc + kk];
        }
        for (int idx = tid; idx < 64 * 16; idx += 256) {
            int r = idx >> 4, c4 = idx & 15;
            int node = nodeBase + r;
            float4 v = make_float4(0.f, 0.f, 0.f, 0.f);
            if (node < n) {
                v = ((const float4*)X)[node * (K / 4) + (kc >> 2) + c4];
                if (doBN) {
                    int f = kc + c4 * 4;
                    v.x = v.x * bnsc[f + 0] + bnsh[f + 0];
                    v.y = v.y * bnsc[f + 1] + bnsh[f + 1];
                    v.z = v.z * bnsc[f + 2] + bnsh[f + 2];
                    v.w = v.w * bnsc[f + 3] + bnsh[f + 3];
                }
            }
            Xt[(c4 * 4 + 0) * SX + r] = v.x;
            Xt[(c4 * 4 + 1) * SX + r] = v.y;
            Xt[(c4 * 4 + 2) * SX + r] = v.z;
            Xt[(c4 * 4 + 3) * SX + r] = v.w;
        }
        __syncthreads();
#pragma unroll 16
        for (int k = 0; k < 64; k++) {
            const float4 xv = *(const float4*)(Xt + k * SX + ty * 4);
            const float4 wv = *(const float4*)(Wt + k * SW + tx * 4);
            const float xa[4] = {xv.x, xv.y, xv.z, xv.w};
            float wa[4 * NF];
            wa[0] = wv.x; wa[1] = wv.y; wa[2] = wv.z; wa[3] = wv.w;
            if constexpr (NF == 2) {
                const float4 wv2 = *(const float4*)(Wt + k * SW + 64 + tx * 4);
                wa[4] = wv2.x; wa[5] = wv2.y; wa[6] = wv2.z; wa[7] = wv2.w;
            }
#pragma unroll
            for (int i = 0; i < 4; i++)
#pragma unroll
                for (int j = 0; j < 4 * NF; j++) acc[i][j] += xa[i] * wa[j];
        }
        __syncthreads();
    }
#pragma unroll
    for (int i = 0; i < 4; i++) {
        int node = nodeBase + ty * 4 + i;
        if (node < n) {
            ushort4 o;
            o.x = f2bf(acc[i][0]); o.y = f2bf(acc[i][1]);
            o.z = f2bf(acc[i][2]); o.w = f2bf(acc[i][3]);
            ((ushort4*)H)[node * (FOUT / 4) + tx] = o;
            if constexpr (NF == 2) {
                ushort4 o2;
                o2.x = f2bf(acc[i][4]); o2.y = f2bf(acc[i][5]);
                o2.z = f2bf(acc[i][6]); o2.w = f2bf(acc[i][7]);
                ((ushort4*)H)[node * (FOUT / 4) + 16 + tx] = o2;
            }
        }
    }
    if (as_o) {
        float asv[4 * NF], adv[4 * NF];
#pragma unroll
        for (int j = 0; j < 4; j++) {
            asv[j] = asrc[tx * 4 + j];
            adv[j] = adst[tx * 4 + j];
            if constexpr (NF == 2) {
                asv[4 + j] = asrc[64 + tx * 4 + j];
                adv[4 + j] = adst[64 + tx * 4 + j];
            }
        }
#pragma unroll
        for (int i = 0; i < 4; i++) {
            int node = nodeBase + ty * 4 + i;
            float ps = 0.f, pd = 0.f;
#pragma unroll
            for (int j = 0; j < 4 * NF; j++) {
                ps += acc[i][j] * asv[j];
                pd += acc[i][j] * adv[j];
            }
#pragma unroll
            for (int off = 1; off < 16; off <<= 1) {
                ps += __shfl_xor(ps, off, 64);
                pd += __shfl_xor(pd, off, 64);
            }
            if (tx == 0 && node < n) {
                as_o[node] = ps;
                ad_o[node] = pd;
            }
        }
    }
}

// ---------------- sparse: group-per-row segment softmax + aggregation (bf16 h) -----------
// Dynamic row stealing: lane 0 of each wave grabs GPW rows via one global atomic,
// broadcast with shfl; groups process their row; early finishers grab more. Perfect balance.

template <int F, bool FINAL>
__global__ __launch_bounds__(256) void edge_kernel(
    const int* __restrict__ rp, const int* __restrict__ srcs, const float* __restrict__ as_,
    const float* __restrict__ ad_, const ushort* __restrict__ h, const float* __restrict__ bias,
    float* __restrict__ y, float* __restrict__ bnsum, float* __restrict__ bnsq,
    const float* __restrict__ xin, float* __restrict__ odiff, float* __restrict__ oxhat,
    int* __restrict__ ctr) {
    constexpr int GS = F / 8;     // lanes per group (one 16B bf16 chunk each)
    constexpr int GPW = 64 / GS;  // groups per wave
    const int tid = threadIdx.x;
    const int lane = tid & 63;
    const int sub = lane & (GS - 1);
    const int gInW = lane / GS;
    const float4 bA = ((const float4*)bias)[sub * 2];
    const float4 bB = ((const float4*)bias)[sub * 2 + 1];
    float st[8], qt[8];
#pragma unroll
    for (int j = 0; j < 8; j++) st[j] = qt[j] = 0.f;

    for (;;) {
        int base = 0;
        if (lane == 0) base = atomicAdd(ctr, GPW);
        base = __shfl(base, 0, 64);
        if (base >= NND) break;
        const int row = base + gInW;
        if (row < NND) {
            const int beg = rp[row], end = rp[row + 1];
            const float ad = ad_[row];
            float a[8];
#pragma unroll
            for (int j = 0; j < 8; j++) a[j] = 0.f;
            float sw = 0.f;
            int i = beg;
            for (; i + 4 <= end; i += 4) {
                int s0 = srcs[i], s1 = srcs[i + 1], s2 = srcs[i + 2], s3 = srcs[i + 3];
                uint4 h0 = *(const uint4*)(h + (size_t)s0 * F + sub * 8);
                uint4 h1 = *(const uint4*)(h + (size_t)s1 * F + sub * 8);
                uint4 h2 = *(const uint4*)(h + (size_t)s2 * F + sub * 8);
                uint4 h3 = *(const uint4*)(h + (size_t)s3 * F + sub * 8);
                float e0 = __expf(fminf(lrelu(as_[s0] + ad), 80.f));
                float e1 = __expf(fminf(lrelu(as_[s1] + ad), 80.f));
                float e2 = __expf(fminf(lrelu(as_[s2] + ad), 80.f));
                float e3 = __expf(fminf(lrelu(as_[s3] + ad), 80.f));
                acc8(a, h0, e0);
                acc8(a, h1, e1);
                acc8(a, h2, e2);
                acc8(a, h3, e3);
                sw += (e0 + e1) + (e2 + e3);
            }
            for (; i < end; i++) {
                int s0 = srcs[i];
                uint4 h0 = *(const uint4*)(h + (size_t)s0 * F + sub * 8);
                float e0 = __expf(fminf(lrelu(as_[s0] + ad), 80.f));
                acc8(a, h0, e0);
                sw += e0;
            }
            const float inv = 1.f / (sw + 1e-16f);
            float4 ya, yb;
            ya.x = fmaxf(a[0] * inv + bA.x, 0.f);
            ya.y = fmaxf(a[1] * inv + bA.y, 0.f);
            ya.z = fmaxf(a[2] * inv + bA.z, 0.f);
            ya.w = fmaxf(a[3] * inv + bA.w, 0.f);
            yb.x = fmaxf(a[4] * inv + bB.x, 0.f);
            yb.y = fmaxf(a[5] * inv + bB.y, 0.f);
            yb.z = fmaxf(a[6] * inv + bB.z, 0.f);
            yb.w = fmaxf(a[7] * inv + bB.w, 0.f);
            if constexpr (FINAL) {
                const float4* xr = (const float4*)(xin + (size_t)row * F);
                float4 xa = xr[sub * 2], xb = xr[sub * 2 + 1];
                float4* xo = (float4*)(oxhat + (size_t)row * F);
                xo[sub * 2] = ya;
                xo[sub * 2 + 1] = yb;
                float4 da, db;
                da.x = fabsf(xa.x - ya.x); da.y = fabsf(xa.y - ya.y);
                da.z = fabsf(xa.z - ya.z); da.w = fabsf(xa.w - ya.w);
                db.x = fabsf(xb.x - yb.x); db.y = fabsf(xb.y - yb.y);
                db.z = fabsf(xb.z - yb.z); db.w = fabsf(xb.w - yb.w);
                float4* dio = (float4*)(odiff + (size_t)row * F);
                dio[sub * 2] = da;
                dio[sub * 2 + 1] = db;
            } else {
                float4* yo = (float4*)(y + (size_t)row * F);
                yo[sub * 2] = ya;
                yo[sub * 2 + 1] = yb;
                st[0] += ya.x; qt[0] += ya.x * ya.x;
                st[1] += ya.y; qt[1] += ya.y * ya.y;
                st[2] += ya.z; qt[2] += ya.z * ya.z;
                st[3] += ya.w; qt[3] += ya.w * ya.w;
                st[4] += yb.x; qt[4] += yb.x * yb.x;
                st[5] += yb.y; qt[5] += yb.y * yb.y;
                st[6] += yb.z; qt[6] += yb.z * yb.z;
                st[7] += yb.w; qt[7] += yb.w * yb.w;
            }
        }
    }
    if constexpr (!FINAL) {
        __shared__ float redS[256][8];
        __shared__ float redQ[256][8];
#pragma unroll
        for (int j = 0; j < 8; j++) {
            redS[tid][j] = st[j];
            redQ[tid][j] = qt[j];
        }
        __syncthreads();
        if (tid < F) {
            int sb = tid >> 3, j = tid & 7;
            float ts = 0.f, tq = 0.f;
            for (int k = 0; k < 256 / GS; k++) {
                int t2 = k * GS + sb;
                ts += redS[t2][j];
                tq += redQ[t2][j];
            }
            atomicAdd(&bnsum[tid], ts);
            atomicAdd(&bnsq[tid], tq);
        }
    }
}

// ---------------- host launch ----------------

extern "C" void kernel_launch(void* const* d_in, const int* in_sizes, int n_in, void* d_out,
                              int out_size, void* d_ws, size_t ws_size, hipStream_t stream) {
    const float* x = (const float*)d_in[0];
    const int* ei = (const int*)d_in[1];
    const int E = in_sizes[1] / 2;
    const float* W1 = (const float*)d_in[2];
    const float* a1s = (const float*)d_in[3];
    const float* a1d = (const float*)d_in[4];
    const float* b1 = (const float*)d_in[5];
    const float* g1 = (const float*)d_in[6];
    const float* be1 = (const float*)d_in[7];
    const float* W2 = (const float*)d_in[8];
    const float* a2s = (const float*)d_in[9];
    const float* a2d = (const float*)d_in[10];
    const float* b2 = (const float*)d_in[11];
    const float* g2 = (const float*)d_in[12];
    const float* be2 = (const float*)d_in[13];
    const float* W3 = (const float*)d_in[14];
    const float* a3s = (const float*)d_in[15];
    const float* a3d = (const float*)d_in[16];
    const float* b3 = (const float*)d_in[17];
    const float* g3 = (const float*)d_in[18];
    const float* be3 = (const float*)d_in[19];
    const float* W4 = (const float*)d_in[20];
    const float* a4s = (const float*)d_in[21];
    const float* a4d = (const float*)d_in[22];
    const float* b4 = (const float*)d_in[23];

    const int Etot = E + NND;

    char* w = (char*)d_ws;
    auto alloc = [&](size_t bytes) {
        void* p = (void*)w;
        w += (bytes + 255) & ~(size_t)255;
        return p;
    };
    // cnt + stats + rowctr contiguous -> one memset clears all
    int* cnt = (int*)alloc((size_t)NND * 4);
    float* stats = (float*)alloc(384 * 4);
    int* rowctr = (int*)alloc(4 * 4);
    int* rp = (int*)alloc((size_t)(NND + 1) * 4);
    int* fill = (int*)alloc((size_t)NND * 4);
    int* bsum = (int*)alloc(256 * 4);
    int* bsum2 = (int*)alloc(256 * 4);
    int* C = (int*)alloc((size_t)NB * SBLK * 4);
    unsigned long long* pairs = (unsigned long long*)alloc((size_t)E * 8);
    int* srcs = (int*)alloc((size_t)Etot * 4);
    ushort* bufH = (ushort*)alloc((size_t)NND * 128 * 2);
    float* bufY = (float*)alloc((size_t)NND * 64 * 4);
    float* asb = (float*)alloc((size_t)NND * 4);
    float* adb = (float*)alloc((size_t)NND * 4);

    const int nblk = (NND + 255) / 256;
    const int ggrid = (NND + 63) / 64;
    const int xgrid = 1024;

    const size_t msz = (((size_t)NND * 4 + 255) & ~(size_t)255) + ((384 * 4 + 255) & ~255) + 256;
    hipError_t _e = hipMemsetAsync(cnt, 0, msz, stream);
    (void)_e;

    countC_kernel<<<SBLK, 256, 0, stream>>>(ei, E, cnt, C);
    scan1_kernel<<<nblk, 256, 0, stream>>>(cnt, NND, rp, bsum);
    scan2_kernel<<<1, 256, 0, stream>>>(bsum, nblk, bsum2);
    scan3_kernel<<<nblk, 256, 0, stream>>>(rp, bsum2, fill, srcs, NND, Etot);
    scanC_kernel<<<1, 1024, 0, stream>>>(C);
    scatter_pairs_kernel<<<SBLK, 256, 0, stream>>>(ei, E, C, pairs);
    bucket_csr_kernel<<<NB, 256, 0, stream>>>(pairs, E, C, fill, srcs);

    // ---- layer 1
    gemm_kernel<128, 64><<<ggrid, 256, 0, stream>>>(x, W1, bufH, NND, nullptr, nullptr, nullptr,
                                                    nullptr, a1s, a1d, asb, adb);
    edge_kernel<64, false><<<xgrid, 256, 0, stream>>>(rp, srcs, asb, adb, bufH, b1, bufY,
                                                      stats + 0, stats + 64, nullptr, nullptr,
                                                      nullptr, rowctr + 0);
    // ---- layer 2 (BN1 fused into gemm staging)
    gemm_kernel<64, 64><<<ggrid, 256, 0, stream>>>(bufY, W2, bufH, NND, stats + 0, stats + 64,
                                                   g1, be1, a2s, a2d, asb, adb);
    edge_kernel<64, false><<<xgrid, 256, 0, stream>>>(rp, srcs, asb, adb, bufH, b2, bufY,
                                                      stats + 128, stats + 192, nullptr, nullptr,
                                                      nullptr, rowctr + 1);
    // ---- layer 3
    gemm_kernel<64, 64><<<ggrid, 256, 0, stream>>>(bufY, W3, bufH, NND, stats + 128, stats + 192,
                                                   g2, be2, a3s, a3d, asb, adb);
    edge_kernel<64, false><<<xgrid, 256, 0, stream>>>(rp, srcs, asb, adb, bufH, b3, bufY,
                                                      stats + 256, stats + 320, nullptr, nullptr,
                                                      nullptr, rowctr + 2);
    // ---- layer 4 (final)
    float* odiff = (float*)d_out;
    float* oxhat = (float*)d_out + (size_t)NND * 128;
    gemm_kernel<64, 128><<<ggrid, 256, 0, stream>>>(bufY, W4, bufH, NND, stats + 256, stats + 320,
                                                    g3, be3, a4s, a4d, asb, adb);
    edge_kernel<128, true><<<xgrid, 256, 0, stream>>>(rp, srcs, asb, adb, bufH, b4, nullptr,
                                                      nullptr, nullptr, x, odiff, oxhat,
                                                      rowctr + 3);
}

// Round 9
// 453.973 us; speedup vs baseline: 1.9476x; 1.9476x over previous
//
#include <hip/hip_runtime.h>
#include <math.h>

#define NND 50000
#define EPSB 1e-5f
#define SLOPE 0.2f
#define NB 256      // dst buckets for counting-sort CSR build
#define SBLK 128    // scatter blocks (chunks of the edge list)
#define BRANGE 196  // nodes per bucket: ceil(50000/256)

__device__ __forceinline__ float lrelu(float v) { return v > 0.f ? v : SLOPE * v; }

__device__ __forceinline__ ushort f2bf(float f) {
    unsigned u = __float_as_uint(f);
    unsigned r = (u + 0x7fffu + ((u >> 16) & 1u)) >> 16;  // RNE
    return (ushort)r;
}

__device__ __forceinline__ void acc8(float* a, uint4 w, float e) {
    a[0] += e * __uint_as_float(w.x << 16);
    a[1] += e * __uint_as_float(w.x & 0xffff0000u);
    a[2] += e * __uint_as_float(w.y << 16);
    a[3] += e * __uint_as_float(w.y & 0xffff0000u);
    a[4] += e * __uint_as_float(w.z << 16);
    a[5] += e * __uint_as_float(w.z & 0xffff0000u);
    a[6] += e * __uint_as_float(w.w << 16);
    a[7] += e * __uint_as_float(w.w & 0xffff0000u);
}

// explicit zeroing (replaces hipMemsetAsync: kernel node has unambiguous capture semantics)
__global__ void zero_kernel(int* __restrict__ cnt, float* __restrict__ stats) {
    int i = blockIdx.x * 256 + threadIdx.x;
    if (i < NND) cnt[i] = 0;
    if (i < 384) stats[i] = 0.f;
}

// ---------------- graph build: counting-sort CSR (write-locality-friendly) ----------------

__global__ __launch_bounds__(256) void countC_kernel(const int* __restrict__ ei, int E,
                                                     int* __restrict__ cnt, int* __restrict__ C) {
    __shared__ int lc[NB];
    const int tid = threadIdx.x;
    for (int i = tid; i < NB; i += 256) lc[i] = 0;
    __syncthreads();
    const int per = (E + SBLK - 1) / SBLK;
    const int beg = blockIdx.x * per;
    const int end = min(beg + per, E);
    for (int i = beg + tid; i < end; i += 256) {
        int d = __builtin_nontemporal_load(&ei[E + i]);
        atomicAdd(&cnt[d], 1);
        atomicAdd(&lc[d / BRANGE], 1);
    }
    __syncthreads();
    for (int i = tid; i < NB; i += 256) C[i * SBLK + blockIdx.x] = lc[i];
}

__global__ __launch_bounds__(1024) void scanC_kernel(int* __restrict__ C) {
    __shared__ int ps[1024];
    const int t = threadIdx.x;
    int v[NB * SBLK / 1024];
    int s = 0;
#pragma unroll
    for (int j = 0; j < NB * SBLK / 1024; j++) {
        v[j] = C[t * (NB * SBLK / 1024) + j];
        s += v[j];
    }
    ps[t] = s;
    __syncthreads();
    for (int off = 1; off < 1024; off <<= 1) {
        int x = (t >= off) ? ps[t - off] : 0;
        __syncthreads();
        ps[t] += x;
        __syncthreads();
    }
    int ex = ps[t] - s;
#pragma unroll
    for (int j = 0; j < NB * SBLK / 1024; j++) {
        int tmp = v[j];
        C[t * (NB * SBLK / 1024) + j] = ex;
        ex += tmp;
    }
}

__global__ __launch_bounds__(256) void scatter_pairs_kernel(const int* __restrict__ ei, int E,
                                                            const int* __restrict__ C,
                                                            unsigned long long* __restrict__ pairs) {
    __shared__ int woff[NB];
    const int tid = threadIdx.x;
    for (int i = tid; i < NB; i += 256) woff[i] = C[i * SBLK + blockIdx.x];
    __syncthreads();
    const int per = (E + SBLK - 1) / SBLK;
    const int beg = blockIdx.x * per;
    const int end = min(beg + per, E);
    for (int i = beg + tid; i < end; i += 256) {
        int s = __builtin_nontemporal_load(&ei[i]);
        int d = __builtin_nontemporal_load(&ei[E + i]);
        int p = atomicAdd(&woff[d / BRANGE], 1);
        p = min(p, E - 1);  // defensive: never write outside pairs
        pairs[p] = ((unsigned long long)(unsigned)d << 32) | (unsigned)s;
    }
}

__global__ void scan1_kernel(const int* __restrict__ in, int n, int* __restrict__ outex,
                             int* __restrict__ bsum) {
    __shared__ int tmp[256];
    int tid = threadIdx.x;
    int i = blockIdx.x * 256 + tid;
    int v = (i < n) ? in[i] + 1 : 0;  // +1 self loop
    tmp[tid] = v;
    __syncthreads();
    for (int off = 1; off < 256; off <<= 1) {
        int t = (tid >= off) ? tmp[tid - off] : 0;
        __syncthreads();
        tmp[tid] += t;
        __syncthreads();
    }
    if (i < n) outex[i] = tmp[tid] - v;
    if (tid == 255) bsum[blockIdx.x] = tmp[255];
}

__global__ void scan2_kernel(const int* __restrict__ in, int n, int* __restrict__ outex) {
    __shared__ int tmp[256];
    int tid = threadIdx.x;
    int v = (tid < n) ? in[tid] : 0;
    tmp[tid] = v;
    __syncthreads();
    for (int off = 1; off < 256; off <<= 1) {
        int t = (tid >= off) ? tmp[tid - off] : 0;
        __syncthreads();
        tmp[tid] += t;
        __syncthreads();
    }
    if (tid < n) outex[tid] = tmp[tid] - v;
}

__global__ void scan3_kernel(int* __restrict__ rp, const int* __restrict__ boff,
                             int* __restrict__ fill, int* __restrict__ srcs, int n, int etot) {
    int i = blockIdx.x * 256 + threadIdx.x;
    if (i < n) {
        int v = rp[i] + boff[blockIdx.x];
        rp[i] = v;
        srcs[v] = i;  // self loop at row head
        fill[i] = v + 1;
    }
    if (i == 0) rp[n] = etot;
}

__global__ __launch_bounds__(256) void bucket_csr_kernel(const unsigned long long* __restrict__ pairs,
                                                         int E, int etot, const int* __restrict__ C,
                                                         int* __restrict__ fill,
                                                         int* __restrict__ srcs) {
    const int b = blockIdx.x;
    const int beg = C[b * SBLK];
    const int end = (b == NB - 1) ? E : C[(b + 1) * SBLK];
    for (int i = beg + threadIdx.x; i < end; i += 256) {
        unsigned long long pr = __builtin_nontemporal_load(&pairs[i]);
        int d = (int)(pr >> 32);
        int s = (int)(pr & 0xffffffffu);
        int p = atomicAdd(&fill[d], 1);
        p = min(p, etot - 1);  // defensive: never write outside srcs
        srcs[p] = s;
    }
}

// ---------------- dense: h = X' @ W^T, fused input-BN, bf16 h output, fused alpha ---------

template <int K, int FOUT>
__global__ __launch_bounds__(256) void gemm_kernel(
    const float* __restrict__ X, const float* __restrict__ W, ushort* __restrict__ H, int n,
    const float* __restrict__ bnsum, const float* __restrict__ bnsq, const float* __restrict__ g,
    const float* __restrict__ be, const float* __restrict__ asrc, const float* __restrict__ adst,
    float* __restrict__ as_o, float* __restrict__ ad_o) {
    constexpr int SW = FOUT + 4;
    constexpr int SX = 68;
    constexpr int NF = FOUT / 64;
    __shared__ float Wt[64 * SW];
    __shared__ float Xt[64 * SX];
    __shared__ float bnsc[K];
    __shared__ float bnsh[K];
    const int tid = threadIdx.x;
    const int nodeBase = blockIdx.x * 64;
    const int tx = tid & 15, ty = tid >> 4;
    const bool doBN = (bnsum != nullptr);

    if (doBN) {
        const float invn = 1.f / (float)NND;
        for (int f = tid; f < K; f += 256) {
            float mu = bnsum[f] * invn;
            float var = bnsq[f] * invn - mu * mu;
            float r = rsqrtf(var + EPSB);
            float sc = g[f] * r;
            bnsc[f] = sc;
            bnsh[f] = be[f] - mu * sc;
        }
    }
    __syncthreads();

    float acc[4][4 * NF];
#pragma unroll
    for (int i = 0; i < 4; i++)
#pragma unroll
        for (int j = 0; j < 4 * NF; j++) acc[i][j] = 0.f;

    for (int kc = 0; kc < K; kc += 64) {
        for (int idx = tid; idx < FOUT * 64; idx += 256) {
            int f = idx >> 6, kk = idx & 63;
            Wt[kk * SW + f] = W[f * K + kc + kk];
        }
        for (int idx = tid; idx < 64 * 16; idx += 256) {
            int r = idx >> 4, c4 = idx & 15;
            int node = nodeBase + r;
            float4 v = make_float4(0.f, 0.f, 0.f, 0.f);
            if (node < n) {
                v = ((const float4*)X)[node * (K / 4) + (kc >> 2) + c4];
                if (doBN) {
                    int f = kc + c4 * 4;
                    v.x = v.x * bnsc[f + 0] + bnsh[f + 0];
                    v.y = v.y * bnsc[f + 1] + bnsh[f + 1];
                    v.z = v.z * bnsc[f + 2] + bnsh[f + 2];
                    v.w = v.w * bnsc[f + 3] + bnsh[f + 3];
                }
            }
            Xt[(c4 * 4 + 0) * SX + r] = v.x;
            Xt[(c4 * 4 + 1) * SX + r] = v.y;
            Xt[(c4 * 4 + 2) * SX + r] = v.z;
            Xt[(c4 * 4 + 3) * SX + r] = v.w;
        }
        __syncthreads();
#pragma unroll 16
        for (int k = 0; k < 64; k++) {
            const float4 xv = *(const float4*)(Xt + k * SX + ty * 4);
            const float4 wv = *(const float4*)(Wt + k * SW + tx * 4);
            const float xa[4] = {xv.x, xv.y, xv.z, xv.w};
            float wa[4 * NF];
            wa[0] = wv.x; wa[1] = wv.y; wa[2] = wv.z; wa[3] = wv.w;
            if constexpr (NF == 2) {
                const float4 wv2 = *(const float4*)(Wt + k * SW + 64 + tx * 4);
                wa[4] = wv2.x; wa[5] = wv2.y; wa[6] = wv2.z; wa[7] = wv2.w;
            }
#pragma unroll
            for (int i = 0; i < 4; i++)
#pragma unroll
                for (int j = 0; j < 4 * NF; j++) acc[i][j] += xa[i] * wa[j];
        }
        __syncthreads();
    }
#pragma unroll
    for (int i = 0; i < 4; i++) {
        int node = nodeBase + ty * 4 + i;
        if (node < n) {
            ushort4 o;
            o.x = f2bf(acc[i][0]); o.y = f2bf(acc[i][1]);
            o.z = f2bf(acc[i][2]); o.w = f2bf(acc[i][3]);
            ((ushort4*)H)[node * (FOUT / 4) + tx] = o;
            if constexpr (NF == 2) {
                ushort4 o2;
                o2.x = f2bf(acc[i][4]); o2.y = f2bf(acc[i][5]);
                o2.z = f2bf(acc[i][6]); o2.w = f2bf(acc[i][7]);
                ((ushort4*)H)[node * (FOUT / 4) + 16 + tx] = o2;
            }
        }
    }
    if (as_o) {
        float asv[4 * NF], adv[4 * NF];
#pragma unroll
        for (int j = 0; j < 4; j++) {
            asv[j] = asrc[tx * 4 + j];
            adv[j] = adst[tx * 4 + j];
            if constexpr (NF == 2) {
                asv[4 + j] = asrc[64 + tx * 4 + j];
                adv[4 + j] = adst[64 + tx * 4 + j];
            }
        }
#pragma unroll
        for (int i = 0; i < 4; i++) {
            int node = nodeBase + ty * 4 + i;
            float ps = 0.f, pd = 0.f;
#pragma unroll
            for (int j = 0; j < 4 * NF; j++) {
                ps += acc[i][j] * asv[j];
                pd += acc[i][j] * adv[j];
            }
#pragma unroll
            for (int off = 1; off < 16; off <<= 1) {
                ps += __shfl_xor(ps, off, 64);
                pd += __shfl_xor(pd, off, 64);
            }
            if (tx == 0 && node < n) {
                as_o[node] = ps;
                ad_o[node] = pd;
            }
        }
    }
}

// ---------------- sparse: group-per-row segment softmax + aggregation (bf16 h) -----------
// Round-4 proven structure: static group->row mapping, plain loads/stores.

template <int F, bool FINAL>
__global__ __launch_bounds__(256) void edge_kernel(
    const int* __restrict__ rp, const int* __restrict__ srcs, const float* __restrict__ as_,
    const float* __restrict__ ad_, const ushort* __restrict__ h, const float* __restrict__ bias,
    float* __restrict__ y, float* __restrict__ bnsum, float* __restrict__ bnsq,
    const float* __restrict__ xin, float* __restrict__ odiff, float* __restrict__ oxhat) {
    constexpr int GS = F / 8;     // lanes per group
    constexpr int GPW = 64 / GS;  // groups per wave
    const int tid = threadIdx.x;
    const int lane = tid & 63;
    const int wslot = tid >> 6;
    const int sub = lane & (GS - 1);
    const int grp = (blockIdx.x * 4 + wslot) * GPW + lane / GS;
    const int ngrp = gridDim.x * 4 * GPW;
    const float4 bA = ((const float4*)bias)[sub * 2];
    const float4 bB = ((const float4*)bias)[sub * 2 + 1];
    float st[8], qt[8];
#pragma unroll
    for (int j = 0; j < 8; j++) st[j] = qt[j] = 0.f;

    for (int row = grp; row < NND; row += ngrp) {
        const int beg = rp[row], end = rp[row + 1];
        const float ad = ad_[row];
        float a[8];
#pragma unroll
        for (int j = 0; j < 8; j++) a[j] = 0.f;
        float sw = 0.f;
        int i = beg;
        for (; i + 4 <= end; i += 4) {
            int s0 = srcs[i], s1 = srcs[i + 1], s2 = srcs[i + 2], s3 = srcs[i + 3];
            uint4 h0 = *(const uint4*)(h + (size_t)s0 * F + sub * 8);
            uint4 h1 = *(const uint4*)(h + (size_t)s1 * F + sub * 8);
            uint4 h2 = *(const uint4*)(h + (size_t)s2 * F + sub * 8);
            uint4 h3 = *(const uint4*)(h + (size_t)s3 * F + sub * 8);
            float e0 = __expf(fminf(lrelu(as_[s0] + ad), 80.f));
            float e1 = __expf(fminf(lrelu(as_[s1] + ad), 80.f));
            float e2 = __expf(fminf(lrelu(as_[s2] + ad), 80.f));
            float e3 = __expf(fminf(lrelu(as_[s3] + ad), 80.f));
            acc8(a, h0, e0);
            acc8(a, h1, e1);
            acc8(a, h2, e2);
            acc8(a, h3, e3);
            sw += (e0 + e1) + (e2 + e3);
        }
        for (; i < end; i++) {
            int s0 = srcs[i];
            uint4 h0 = *(const uint4*)(h + (size_t)s0 * F + sub * 8);
            float e0 = __expf(fminf(lrelu(as_[s0] + ad), 80.f));
            acc8(a, h0, e0);
            sw += e0;
        }
        const float inv = 1.f / (sw + 1e-16f);
        float4 ya, yb;
        ya.x = fmaxf(a[0] * inv + bA.x, 0.f);
        ya.y = fmaxf(a[1] * inv + bA.y, 0.f);
        ya.z = fmaxf(a[2] * inv + bA.z, 0.f);
        ya.w = fmaxf(a[3] * inv + bA.w, 0.f);
        yb.x = fmaxf(a[4] * inv + bB.x, 0.f);
        yb.y = fmaxf(a[5] * inv + bB.y, 0.f);
        yb.z = fmaxf(a[6] * inv + bB.z, 0.f);
        yb.w = fmaxf(a[7] * inv + bB.w, 0.f);
        if constexpr (FINAL) {
            const float4* xr = (const float4*)(xin + (size_t)row * F);
            float4 xa = xr[sub * 2], xb = xr[sub * 2 + 1];
            float4* xo = (float4*)(oxhat + (size_t)row * F);
            xo[sub * 2] = ya;
            xo[sub * 2 + 1] = yb;
            float4 da, db;
            da.x = fabsf(xa.x - ya.x); da.y = fabsf(xa.y - ya.y);
            da.z = fabsf(xa.z - ya.z); da.w = fabsf(xa.w - ya.w);
            db.x = fabsf(xb.x - yb.x); db.y = fabsf(xb.y - yb.y);
            db.z = fabsf(xb.z - yb.z); db.w = fabsf(xb.w - yb.w);
            float4* dio = (float4*)(odiff + (size_t)row * F);
            dio[sub * 2] = da;
            dio[sub * 2 + 1] = db;
        } else {
            float4* yo = (float4*)(y + (size_t)row * F);
            yo[sub * 2] = ya;
            yo[sub * 2 + 1] = yb;
            st[0] += ya.x; qt[0] += ya.x * ya.x;
            st[1] += ya.y; qt[1] += ya.y * ya.y;
            st[2] += ya.z; qt[2] += ya.z * ya.z;
            st[3] += ya.w; qt[3] += ya.w * ya.w;
            st[4] += yb.x; qt[4] += yb.x * yb.x;
            st[5] += yb.y; qt[5] += yb.y * yb.y;
            st[6] += yb.z; qt[6] += yb.z * yb.z;
            st[7] += yb.w; qt[7] += yb.w * yb.w;
        }
    }
    if constexpr (!FINAL) {
        __shared__ float redS[256][8];
        __shared__ float redQ[256][8];
#pragma unroll
        for (int j = 0; j < 8; j++) {
            redS[tid][j] = st[j];
            redQ[tid][j] = qt[j];
        }
        __syncthreads();
        if (tid < F) {
            int sb = tid >> 3, j = tid & 7;
            float ts = 0.f, tq = 0.f;
            for (int k = 0; k < 256 / GS; k++) {
                int t2 = k * GS + sb;
                ts += redS[t2][j];
                tq += redQ[t2][j];
            }
            atomicAdd(&bnsum[tid], ts);
            atomicAdd(&bnsq[tid], tq);
        }
    }
}

// ---------------- host launch ----------------

extern "C" void kernel_launch(void* const* d_in, const int* in_sizes, int n_in, void* d_out,
                              int out_size, void* d_ws, size_t ws_size, hipStream_t stream) {
    const float* x = (const float*)d_in[0];
    const int* ei = (const int*)d_in[1];
    const int E = in_sizes[1] / 2;
    const float* W1 = (const float*)d_in[2];
    const float* a1s = (const float*)d_in[3];
    const float* a1d = (const float*)d_in[4];
    const float* b1 = (const float*)d_in[5];
    const float* g1 = (const float*)d_in[6];
    const float* be1 = (const float*)d_in[7];
    const float* W2 = (const float*)d_in[8];
    const float* a2s = (const float*)d_in[9];
    const float* a2d = (const float*)d_in[10];
    const float* b2 = (const float*)d_in[11];
    const float* g2 = (const float*)d_in[12];
    const float* be2 = (const float*)d_in[13];
    const float* W3 = (const float*)d_in[14];
    const float* a3s = (const float*)d_in[15];
    const float* a3d = (const float*)d_in[16];
    const float* b3 = (const float*)d_in[17];
    const float* g3 = (const float*)d_in[18];
    const float* be3 = (const float*)d_in[19];
    const float* W4 = (const float*)d_in[20];
    const float* a4s = (const float*)d_in[21];
    const float* a4d = (const float*)d_in[22];
    const float* b4 = (const float*)d_in[23];

    const int Etot = E + NND;

    char* w = (char*)d_ws;
    auto alloc = [&](size_t bytes) {
        void* p = (void*)w;
        w += (bytes + 255) & ~(size_t)255;
        return p;
    };
    int* cnt = (int*)alloc((size_t)NND * 4);
    float* stats = (float*)alloc(384 * 4);
    int* rp = (int*)alloc((size_t)(NND + 1) * 4);
    int* fill = (int*)alloc((size_t)NND * 4);
    int* bsum = (int*)alloc(256 * 4);
    int* bsum2 = (int*)alloc(256 * 4);
    int* C = (int*)alloc((size_t)NB * SBLK * 4);
    unsigned long long* pairs = (unsigned long long*)alloc((size_t)E * 8);
    int* srcs = (int*)alloc((size_t)Etot * 4);
    ushort* bufH = (ushort*)alloc((size_t)NND * 128 * 2);
    float* bufY = (float*)alloc((size_t)NND * 64 * 4);
    float* asb = (float*)alloc((size_t)NND * 4);
    float* adb = (float*)alloc((size_t)NND * 4);

    const int nblk = (NND + 255) / 256;
    const int ggrid = (NND + 63) / 64;
    const int xgrid = 1024;

    zero_kernel<<<nblk, 256, 0, stream>>>(cnt, stats);
    countC_kernel<<<SBLK, 256, 0, stream>>>(ei, E, cnt, C);
    scan1_kernel<<<nblk, 256, 0, stream>>>(cnt, NND, rp, bsum);
    scan2_kernel<<<1, 256, 0, stream>>>(bsum, nblk, bsum2);
    scan3_kernel<<<nblk, 256, 0, stream>>>(rp, bsum2, fill, srcs, NND, Etot);
    scanC_kernel<<<1, 1024, 0, stream>>>(C);
    scatter_pairs_kernel<<<SBLK, 256, 0, stream>>>(ei, E, C, pairs);
    bucket_csr_kernel<<<NB, 256, 0, stream>>>(pairs, E, Etot, C, fill, srcs);

    // ---- layer 1
    gemm_kernel<128, 64><<<ggrid, 256, 0, stream>>>(x, W1, bufH, NND, nullptr, nullptr, nullptr,
                                                    nullptr, a1s, a1d, asb, adb);
    edge_kernel<64, false><<<xgrid, 256, 0, stream>>>(rp, srcs, asb, adb, bufH, b1, bufY,
                                                      stats + 0, stats + 64, nullptr, nullptr,
                                                      nullptr);
    // ---- layer 2 (BN1 fused into gemm staging)
    gemm_kernel<64, 64><<<ggrid, 256, 0, stream>>>(bufY, W2, bufH, NND, stats + 0, stats + 64,
                                                   g1, be1, a2s, a2d, asb, adb);
    edge_kernel<64, false><<<xgrid, 256, 0, stream>>>(rp, srcs, asb, adb, bufH, b2, bufY,
                                                      stats + 128, stats + 192, nullptr, nullptr,
                                                      nullptr);
    // ---- layer 3
    gemm_kernel<64, 64><<<ggrid, 256, 0, stream>>>(bufY, W3, bufH, NND, stats + 128, stats + 192,
                                                   g2, be2, a3s, a3d, asb, adb);
    edge_kernel<64, false><<<xgrid, 256, 0, stream>>>(rp, srcs, asb, adb, bufH, b3, bufY,
                                                      stats + 256, stats + 320, nullptr, nullptr,
                                                      nullptr);
    // ---- layer 4 (final)
    float* odiff = (float*)d_out;
    float* oxhat = (float*)d_out + (size_t)NND * 128;
    gemm_kernel<64, 128><<<ggrid, 256, 0, stream>>>(bufY, W4, bufH, NND, stats + 256, stats + 320,
                                                    g3, be3, a4s, a4d, asb, adb);
    edge_kernel<128, true><<<xgrid, 256, 0, stream>>>(rp, srcs, asb, adb, bufH, b4, nullptr,
                                                      nullptr, nullptr, x, odiff, oxhat);
}